// Round 1
// baseline (289.581 us; speedup 1.0000x reference)
//
#include <hip/hip_runtime.h>

// ---------- types & helpers ----------
typedef float f32x4 __attribute__((ext_vector_type(4)));
typedef __bf16 bf16x8 __attribute__((ext_vector_type(8)));
typedef unsigned short u16x8 __attribute__((ext_vector_type(8)));

__device__ __forceinline__ unsigned short f2bf(float x) {
  unsigned int u = __float_as_uint(x);
  u += 0x7FFFu + ((u >> 16) & 1u);   // round-to-nearest-even
  return (unsigned short)(u >> 16);
}
__device__ __forceinline__ float bf2f(unsigned short h) {
  return __uint_as_float(((unsigned int)h) << 16);
}
#define MFMA16(a, b, c) __builtin_amdgcn_mfma_f32_16x16x32_bf16((a), (b), (c), 0, 0, 0)

// sizes
#define SEQ 1024
#define NB 4
#define NH 12
#define HD 64
#define HID 768
#define N1 2304
#define MTOT 8192  // 2 modalities * 4096 rows

// ---------- weight convert: qkv_w [768][2304] fp32 -> w1t [2304][768] bf16 ----------
__global__ void k_conv_w1(const float* __restrict__ w, unsigned short* __restrict__ wt) {
  int idx = blockIdx.x * 256 + threadIdx.x;  // output-contiguous
  if (idx >= N1 * HID) return;
  int n = idx / HID, k = idx % HID;
  wt[idx] = f2bf(w[(size_t)k * N1 + n]);
}

// out_w [768][768] fp32 -> hi/lo bf16 [768 n][768 k]
__global__ void k_conv_w2(const float* __restrict__ w, unsigned short* __restrict__ hi,
                          unsigned short* __restrict__ lo) {
  int idx = blockIdx.x * 256 + threadIdx.x;
  if (idx >= HID * HID) return;
  int n = idx / HID, k = idx % HID;
  float x = w[(size_t)k * HID + n];
  unsigned short h = f2bf(x);
  hi[idx] = h;
  lo[idx] = f2bf(x - bf2f(h));
}

// ---------- QKV GEMM: [8192 x 768] @ [768 x 2304], scatter to Q/K/V bf16 ----------
__global__ __launch_bounds__(256, 2) void k_qkv(
    const float* __restrict__ img, const float* __restrict__ dpt,
    const unsigned short* __restrict__ w1t, const float* __restrict__ qkvb,
    unsigned short* __restrict__ Qb, unsigned short* __restrict__ Kb,
    unsigned short* __restrict__ Vb) {
  __shared__ unsigned short As[128][72];
  __shared__ unsigned short Bs[128][72];
  const int tid = threadIdx.x, lane = tid & 63, wid = tid >> 6;
  const int wr = (wid >> 1) * 64, wc = (wid & 1) * 64;
  const int l15 = lane & 15, lg = lane >> 4;
  const int bn = blockIdx.x, bm = blockIdx.y;
  const float* Abase = (bm < 32) ? img : dpt;
  const int mbase = (bm & 31) * 128;
  const int mod = bm >> 5;

  f32x4 zero = {0.f, 0.f, 0.f, 0.f};
  f32x4 acc[4][4];
#pragma unroll
  for (int i = 0; i < 4; i++)
#pragma unroll
    for (int j = 0; j < 4; j++) acc[i][j] = zero;

  for (int kt = 0; kt < 12; ++kt) {
    __syncthreads();
    // stage A (fp32 -> bf16), 128x64, b128 LDS writes
#pragma unroll
    for (int i = 0; i < 4; i++) {
      int g = i * 256 + tid;  // 0..1023
      int row = g >> 3, c8 = (g & 7) * 8;
      const float4 v0 = *(const float4*)&Abase[(size_t)(mbase + row) * HID + kt * 64 + c8];
      const float4 v1 = *(const float4*)&Abase[(size_t)(mbase + row) * HID + kt * 64 + c8 + 4];
      u16x8 o;
      o[0] = f2bf(v0.x); o[1] = f2bf(v0.y); o[2] = f2bf(v0.z); o[3] = f2bf(v0.w);
      o[4] = f2bf(v1.x); o[5] = f2bf(v1.y); o[6] = f2bf(v1.z); o[7] = f2bf(v1.w);
      *(u16x8*)&As[row][c8] = o;
    }
    // stage B (already transposed bf16 [N][K])
#pragma unroll
    for (int i = 0; i < 4; i++) {
      int g = i * 256 + tid;  // 0..1023
      int row = g >> 3, c8 = (g & 7) * 8;
      u16x8 v = *(const u16x8*)&w1t[(size_t)(bn * 128 + row) * HID + kt * 64 + c8];
      *(u16x8*)&Bs[row][c8] = v;
    }
    __syncthreads();
#pragma unroll
    for (int ks = 0; ks < 2; ++ks) {
      bf16x8 a[4], b[4];
#pragma unroll
      for (int bi = 0; bi < 4; bi++) a[bi] = *(const bf16x8*)&As[wr + bi * 16 + l15][lg * 8 + ks * 32];
#pragma unroll
      for (int bj = 0; bj < 4; bj++) b[bj] = *(const bf16x8*)&Bs[wc + bj * 16 + l15][lg * 8 + ks * 32];
#pragma unroll
      for (int bi = 0; bi < 4; bi++)
#pragma unroll
        for (int bj = 0; bj < 4; bj++) acc[bi][bj] = MFMA16(a[bi], b[bj], acc[bi][bj]);
    }
  }
  // epilogue: +bias, Q*=0.125, scatter to [mod][b][h][s][d]
#pragma unroll
  for (int bj = 0; bj < 4; bj++) {
    int n = bn * 128 + wc + bj * 16 + l15;
    float bias = qkvb[n];
    int which = (n >= 1536) ? 2 : (n >= 768 ? 1 : 0);
    int c = n - which * 768;
    int h = c >> 6, d = c & 63;
    unsigned short* dst = which == 0 ? Qb : (which == 1 ? Kb : Vb);
    float scale = (which == 0) ? 0.125f : 1.0f;
#pragma unroll
    for (int bi = 0; bi < 4; bi++) {
#pragma unroll
      for (int r = 0; r < 4; r++) {
        int rowm = mbase + wr + bi * 16 + lg * 4 + r;  // 0..4095 within modality
        int bb = rowm >> 10, s = rowm & 1023;
        float val = (acc[bi][bj][r] + bias) * scale;
        dst[(((size_t)(mod * NB + bb) * NH + h) * SEQ + s) * HD + d] = f2bf(val);
      }
    }
  }
}

// ---------- fused dual-modality flash attention ----------
__global__ __launch_bounds__(256, 2) void k_attn(
    const unsigned short* __restrict__ Qb, const unsigned short* __restrict__ Kb,
    const unsigned short* __restrict__ Vb, float* __restrict__ ctx) {
  __shared__ unsigned short Ks[2][64][72];
  __shared__ unsigned short Vts[2][64][72];
  __shared__ unsigned short Ps[4][2][16][72];
  const int tid = threadIdx.x, lane = tid & 63, wid = tid >> 6;
  const int l15 = lane & 15, lg = lane >> 4;
  const int qt = blockIdx.x, bh = blockIdx.y;  // bh = b*12 + h

  // Q fragments (A-operand), per modality, per 32-wide k-step
  bf16x8 qf[2][2];
#pragma unroll
  for (int mod = 0; mod < 2; mod++) {
    size_t base = ((size_t)(mod * 48 + bh) * SEQ + qt * 64 + wid * 16 + l15) * HD;
#pragma unroll
    for (int ks = 0; ks < 2; ks++) qf[mod][ks] = *(const bf16x8*)&Qb[base + lg * 8 + ks * 32];
  }

  float m_[2][4], l_[2][4];
#pragma unroll
  for (int mod = 0; mod < 2; mod++)
#pragma unroll
    for (int r = 0; r < 4; r++) { m_[mod][r] = -1e30f; l_[mod][r] = 0.f; }
  f32x4 zero = {0.f, 0.f, 0.f, 0.f};
  f32x4 O[2][2][4];  // [p-mod][v-mod][d-block]
#pragma unroll
  for (int a = 0; a < 2; a++)
#pragma unroll
    for (int v = 0; v < 2; v++)
#pragma unroll
      for (int c = 0; c < 4; c++) O[a][v][c] = zero;

  for (int kt = 0; kt < 16; ++kt) {
    __syncthreads();
    // stage K (row-major) and V^T (rotation-swizzled scalar writes) for both mods
#pragma unroll
    for (int mod = 0; mod < 2; mod++) {
      size_t kbase = ((size_t)(mod * 48 + bh) * SEQ + kt * 64) * HD;
#pragma unroll
      for (int i = 0; i < 2; i++) {
        int g = i * 256 + tid;  // 0..511
        int row = g >> 3, c8 = (g & 7) * 8;
        u16x8 kv = *(const u16x8*)&Kb[kbase + row * HD + c8];
        *(u16x8*)&Ks[mod][row][c8] = kv;
        u16x8 vv = *(const u16x8*)&Vb[kbase + row * HD + c8];
#pragma unroll
        for (int jj = 0; jj < 8; jj++) {
          int j = (jj + (tid & 7)) & 7;  // rotate to spread banks
          Vts[mod][c8 + j][row] = vv[j];
        }
      }
    }
    __syncthreads();
    // QK^T + online softmax per modality
#pragma unroll
    for (int mod = 0; mod < 2; mod++) {
      f32x4 s[4];
#pragma unroll
      for (int kb = 0; kb < 4; kb++) s[kb] = zero;
#pragma unroll
      for (int ks = 0; ks < 2; ks++) {
#pragma unroll
        for (int kb = 0; kb < 4; kb++) {
          bf16x8 kf = *(const bf16x8*)&Ks[mod][kb * 16 + l15][lg * 8 + ks * 32];
          s[kb] = MFMA16(qf[mod][ks], kf, s[kb]);
        }
      }
      float tm[4], p[4][4], rs[4], sc[4];
#pragma unroll
      for (int r = 0; r < 4; r++)
        tm[r] = fmaxf(fmaxf(s[0][r], s[1][r]), fmaxf(s[2][r], s[3][r]));
#pragma unroll
      for (int r = 0; r < 4; r++) {
#pragma unroll
        for (int msk = 1; msk < 16; msk <<= 1) tm[r] = fmaxf(tm[r], __shfl_xor(tm[r], msk));
      }
#pragma unroll
      for (int r = 0; r < 4; r++) {
        float mn = fmaxf(m_[mod][r], tm[r]);
        sc[r] = __expf(m_[mod][r] - mn);
        m_[mod][r] = mn;
        rs[r] = 0.f;
#pragma unroll
        for (int kb = 0; kb < 4; kb++) {
          p[kb][r] = __expf(s[kb][r] - mn);
          rs[r] += p[kb][r];
        }
      }
#pragma unroll
      for (int r = 0; r < 4; r++) {
#pragma unroll
        for (int msk = 1; msk < 16; msk <<= 1) rs[r] += __shfl_xor(rs[r], msk);
        l_[mod][r] = l_[mod][r] * sc[r] + rs[r];
      }
#pragma unroll
      for (int v = 0; v < 2; v++)
#pragma unroll
        for (int db = 0; db < 4; db++)
#pragma unroll
          for (int r = 0; r < 4; r++) O[mod][v][db][r] *= sc[r];
#pragma unroll
      for (int kb = 0; kb < 4; kb++)
#pragma unroll
        for (int r = 0; r < 4; r++)
          Ps[wid][mod][lg * 4 + r][kb * 16 + l15] = f2bf(p[kb][r]);
    }
    __syncthreads();
    // PV: 4 combinations
#pragma unroll
    for (int pm = 0; pm < 2; pm++) {
#pragma unroll
      for (int ks = 0; ks < 2; ks++) {
        bf16x8 af = *(const bf16x8*)&Ps[wid][pm][l15][lg * 8 + ks * 32];
#pragma unroll
        for (int vm = 0; vm < 2; vm++) {
#pragma unroll
          for (int db = 0; db < 4; db++) {
            bf16x8 vf = *(const bf16x8*)&Vts[vm][db * 16 + l15][lg * 8 + ks * 32];
            O[pm][vm][db] = MFMA16(af, vf, O[pm][vm][db]);
          }
        }
      }
    }
  }
  // finalize: blend & write ctx fp32 [mod][b][s][h*64+d]
  const int bb = bh / 12, h = bh % 12;
  float inv[2][4];
#pragma unroll
  for (int mod = 0; mod < 2; mod++)
#pragma unroll
    for (int r = 0; r < 4; r++) inv[mod][r] = 1.f / l_[mod][r];
  const int qrow = qt * 64 + wid * 16 + lg * 4;
#pragma unroll
  for (int db = 0; db < 4; db++) {
#pragma unroll
    for (int r = 0; r < 4; r++) {
      int s = qrow + r;
      float ci = 0.7f * O[0][0][db][r] * inv[0][r] + 0.3f * O[1][0][db][r] * inv[1][r];
      float cd = 0.7f * O[1][1][db][r] * inv[1][r] + 0.3f * O[0][1][db][r] * inv[0][r];
      size_t col = h * 64 + db * 16 + l15;
      ctx[((size_t)(bb * SEQ + s)) * HID + col] = ci;
      ctx[((size_t)(4096 + bb * SEQ + s)) * HID + col] = cd;
    }
  }
}

// ---------- out projection: split-bf16 (hi/lo) 3-product GEMM, BK=32 ----------
__global__ __launch_bounds__(256, 2) void k_outproj(
    const float* __restrict__ ctx, const unsigned short* __restrict__ whi,
    const unsigned short* __restrict__ wlo, const float* __restrict__ outb,
    float* __restrict__ out) {
  __shared__ unsigned short Ahi[128][40], Alo[128][40], Bhi[128][40], Blo[128][40];
  const int tid = threadIdx.x, lane = tid & 63, wid = tid >> 6;
  const int wr = (wid >> 1) * 64, wc = (wid & 1) * 64;
  const int l15 = lane & 15, lg = lane >> 4;
  const int bn = blockIdx.x, bm = blockIdx.y;
  f32x4 zero = {0.f, 0.f, 0.f, 0.f};
  f32x4 acc[4][4];
#pragma unroll
  for (int i = 0; i < 4; i++)
#pragma unroll
    for (int j = 0; j < 4; j++) acc[i][j] = zero;

  for (int kt = 0; kt < 24; ++kt) {
    __syncthreads();
#pragma unroll
    for (int i = 0; i < 2; i++) {
      int g = i * 256 + tid;  // 0..511: 128 rows x 4 groups
      int row = g >> 2, c8 = (g & 3) * 8;
      const float4 v0 = *(const float4*)&ctx[(size_t)(bm * 128 + row) * HID + kt * 32 + c8];
      const float4 v1 = *(const float4*)&ctx[(size_t)(bm * 128 + row) * HID + kt * 32 + c8 + 4];
      float xs[8] = {v0.x, v0.y, v0.z, v0.w, v1.x, v1.y, v1.z, v1.w};
      u16x8 hv, lv;
#pragma unroll
      for (int j = 0; j < 8; j++) {
        unsigned short hh = f2bf(xs[j]);
        hv[j] = hh;
        lv[j] = f2bf(xs[j] - bf2f(hh));
      }
      *(u16x8*)&Ahi[row][c8] = hv;
      *(u16x8*)&Alo[row][c8] = lv;
      u16x8 bh_ = *(const u16x8*)&whi[(size_t)(bn * 128 + row) * HID + kt * 32 + c8];
      u16x8 bl_ = *(const u16x8*)&wlo[(size_t)(bn * 128 + row) * HID + kt * 32 + c8];
      *(u16x8*)&Bhi[row][c8] = bh_;
      *(u16x8*)&Blo[row][c8] = bl_;
    }
    __syncthreads();
    bf16x8 ah[4], al[4], bh2[4], bl2[4];
#pragma unroll
    for (int bi = 0; bi < 4; bi++) {
      ah[bi] = *(const bf16x8*)&Ahi[wr + bi * 16 + l15][lg * 8];
      al[bi] = *(const bf16x8*)&Alo[wr + bi * 16 + l15][lg * 8];
    }
#pragma unroll
    for (int bj = 0; bj < 4; bj++) {
      bh2[bj] = *(const bf16x8*)&Bhi[wc + bj * 16 + l15][lg * 8];
      bl2[bj] = *(const bf16x8*)&Blo[wc + bj * 16 + l15][lg * 8];
    }
#pragma unroll
    for (int bi = 0; bi < 4; bi++)
#pragma unroll
      for (int bj = 0; bj < 4; bj++) {
        acc[bi][bj] = MFMA16(ah[bi], bh2[bj], acc[bi][bj]);
        acc[bi][bj] = MFMA16(ah[bi], bl2[bj], acc[bi][bj]);
        acc[bi][bj] = MFMA16(al[bi], bh2[bj], acc[bi][bj]);
      }
  }
#pragma unroll
  for (int bj = 0; bj < 4; bj++) {
    int n = bn * 128 + wc + bj * 16 + l15;
    float bias = outb[n];
#pragma unroll
    for (int bi = 0; bi < 4; bi++) {
#pragma unroll
      for (int r = 0; r < 4; r++) {
        int m = bm * 128 + wr + bi * 16 + lg * 4 + r;
        int mod = m >> 12, mm = m & 4095;
        out[(size_t)mod * 3145728 + (size_t)mm * HID + n] = acc[bi][bj][r] + bias;
      }
    }
  }
}

// ---------- launcher ----------
extern "C" void kernel_launch(void* const* d_in, const int* in_sizes, int n_in,
                              void* d_out, int out_size, void* d_ws, size_t ws_size,
                              hipStream_t stream) {
  const float* img = (const float*)d_in[0];
  const float* dpt = (const float*)d_in[1];
  const float* qkv_w = (const float*)d_in[2];
  const float* qkv_b = (const float*)d_in[3];
  const float* out_w = (const float*)d_in[4];
  const float* out_b = (const float*)d_in[5];
  float* out = (float*)d_out;

  char* ws = (char*)d_ws;
  size_t off = 0;
  unsigned short* w1t = (unsigned short*)(ws + off); off += (size_t)N1 * HID * 2;      // 3.54 MB
  unsigned short* w2hi = (unsigned short*)(ws + off); off += (size_t)HID * HID * 2;    // 1.18 MB
  unsigned short* w2lo = (unsigned short*)(ws + off); off += (size_t)HID * HID * 2;
  unsigned short* Qb = (unsigned short*)(ws + off); off += (size_t)2 * 48 * SEQ * HD * 2;
  unsigned short* Kb = (unsigned short*)(ws + off); off += (size_t)2 * 48 * SEQ * HD * 2;
  unsigned short* Vb = (unsigned short*)(ws + off); off += (size_t)2 * 48 * SEQ * HD * 2;
  float* ctx = (float*)(ws + off); off += (size_t)MTOT * HID * 4;                      // 25.2 MB
  if (ws_size < off) return;  // workspace too small -> visible failure

  k_conv_w1<<<(N1 * HID + 255) / 256, 256, 0, stream>>>(qkv_w, w1t);
  k_conv_w2<<<(HID * HID + 255) / 256, 256, 0, stream>>>(out_w, w2hi, w2lo);
  k_qkv<<<dim3(18, 64), 256, 0, stream>>>(img, dpt, w1t, qkv_b, Qb, Kb, Vb);
  k_attn<<<dim3(16, 48), 256, 0, stream>>>(Qb, Kb, Vb, ctx);
  k_outproj<<<dim3(6, 64), 256, 0, stream>>>(ctx, w2hi, w2lo, out_b, out);
}

// Round 2
// 197.612 us; speedup vs baseline: 1.4654x; 1.4654x over previous
//
#include <hip/hip_runtime.h>

// ---------- types & helpers ----------
typedef float f32x4 __attribute__((ext_vector_type(4)));
typedef __bf16 bf16x8 __attribute__((ext_vector_type(8)));
typedef unsigned short u16x8 __attribute__((ext_vector_type(8)));
typedef unsigned short u16x4 __attribute__((ext_vector_type(4)));

__device__ __forceinline__ unsigned short f2bf(float x) {
  unsigned int u = __float_as_uint(x);
  u += 0x7FFFu + ((u >> 16) & 1u);  // RNE
  return (unsigned short)(u >> 16);
}
__device__ __forceinline__ float bf2f(unsigned short h) {
  return __uint_as_float(((unsigned int)h) << 16);
}
#define MFMA16(a, b, c) __builtin_amdgcn_mfma_f32_16x16x32_bf16((a), (b), (c), 0, 0, 0)

// async global->LDS, 16B per lane; dest = wave-uniform base + lane*16 (linear).
// Swizzle is applied on the GLOBAL source address (rule: both-sides-or-neither).
#define GLOAD_LDS16(gp, lp)                                                    \
  __builtin_amdgcn_global_load_lds(                                            \
      (const __attribute__((address_space(1))) unsigned int*)(gp),             \
      (__attribute__((address_space(3))) unsigned int*)(lp), 16, 0, 0)

#define SEQ 1024
#define NB 4
#define NH 12
#define HD 64
#define HID 768
#define N1 2304
// Q pre-scale: (1/sqrt(64)) * log2(e)  -> softmax runs in exp2 domain
#define QSCALE 0.18033688011112042f

// ---------- input convert: img|dpt fp32 -> Xb bf16 [8192][768] ----------
__global__ void k_conv_x(const float* __restrict__ img, const float* __restrict__ dpt,
                         unsigned short* __restrict__ Xb) {
  size_t e = ((size_t)blockIdx.x * 256 + threadIdx.x) * 8;
  const float* src = (e < 3145728) ? (img + e) : (dpt + (e - 3145728));
  float4 v0 = *(const float4*)src;
  float4 v1 = *(const float4*)(src + 4);
  u16x8 o;
  o[0] = f2bf(v0.x); o[1] = f2bf(v0.y); o[2] = f2bf(v0.z); o[3] = f2bf(v0.w);
  o[4] = f2bf(v1.x); o[5] = f2bf(v1.y); o[6] = f2bf(v1.z); o[7] = f2bf(v1.w);
  *(u16x8*)&Xb[e] = o;
}

// ---------- weight transpose (LDS tiled): qkv_w [768][2304] -> w1t [2304][768] bf16 ----------
__global__ void k_trans_w1(const float* __restrict__ w, unsigned short* __restrict__ wt) {
  __shared__ float t[64][65];
  const int n0 = blockIdx.x * 64, k0 = blockIdx.y * 64;
  const int c = threadIdx.x & 63, rq = threadIdx.x >> 6;
#pragma unroll
  for (int i = 0; i < 16; i++) {
    int r = i * 4 + rq;
    t[r][c] = w[(size_t)(k0 + r) * N1 + n0 + c];
  }
  __syncthreads();
#pragma unroll
  for (int i = 0; i < 16; i++) {
    int r = i * 4 + rq;
    wt[(size_t)(n0 + r) * HID + k0 + c] = f2bf(t[c][r]);
  }
}

// out_w [768][768] -> hi/lo bf16 [n][k]
__global__ void k_trans_w2(const float* __restrict__ w, unsigned short* __restrict__ hi,
                           unsigned short* __restrict__ lo) {
  __shared__ float t[64][65];
  const int n0 = blockIdx.x * 64, k0 = blockIdx.y * 64;
  const int c = threadIdx.x & 63, rq = threadIdx.x >> 6;
#pragma unroll
  for (int i = 0; i < 16; i++) {
    int r = i * 4 + rq;
    t[r][c] = w[(size_t)(k0 + r) * HID + n0 + c];
  }
  __syncthreads();
#pragma unroll
  for (int i = 0; i < 16; i++) {
    int r = i * 4 + rq;
    float x = t[c][r];
    unsigned short h = f2bf(x);
    hi[(size_t)(n0 + r) * HID + k0 + c] = h;
    lo[(size_t)(n0 + r) * HID + k0 + c] = f2bf(x - bf2f(h));
  }
}

// ---------- QKV GEMM: Xb[8192x768]bf16 @ w1t -> Q/K bf16 [mod][b][h][s][d], V^T [mod][b][h][d][s] ----------
__global__ __launch_bounds__(256, 2) void k_qkv(
    const unsigned short* __restrict__ Xb, const unsigned short* __restrict__ w1t,
    const float* __restrict__ qkvb, unsigned short* __restrict__ Qb,
    unsigned short* __restrict__ Kb, unsigned short* __restrict__ Vb) {
  __shared__ unsigned short As[128 * 64];  // swizzled: slot(row,c16) holds col (c16^(row&7))
  __shared__ unsigned short Bs[128 * 64];
  const int tid = threadIdx.x, lane = tid & 63, wid = tid >> 6;
  const int wr = (wid >> 1) * 64, wc = (wid & 1) * 64;
  const int l15 = lane & 15, lg = lane >> 4;
  const int bn = blockIdx.x, bm = blockIdx.y;
  const int mod = bm >> 5, mbase = (bm & 31) * 128;

  f32x4 zero = {0.f, 0.f, 0.f, 0.f};
  f32x4 acc[4][4];
#pragma unroll
  for (int i = 0; i < 4; i++)
#pragma unroll
    for (int j = 0; j < 4; j++) acc[i][j] = zero;

  for (int kt = 0; kt < 12; ++kt) {
    __syncthreads();
#pragma unroll
    for (int j = 0; j < 4; j++) {
      const int Lb = wid * 4096 + j * 1024 + lane * 16;
      const int row = Lb >> 7, c16 = (Lb >> 4) & 7;
      const int sc16 = c16 ^ (row & 7);
      GLOAD_LDS16(Xb + (size_t)(bm * 128 + row) * HID + kt * 64 + sc16 * 8,
                  (char*)As + (wid * 4096 + j * 1024));
      GLOAD_LDS16(w1t + (size_t)(bn * 128 + row) * HID + kt * 64 + sc16 * 8,
                  (char*)Bs + (wid * 4096 + j * 1024));
    }
    __syncthreads();
#pragma unroll
    for (int ks = 0; ks < 2; ++ks) {
      bf16x8 a[4], b[4];
#pragma unroll
      for (int bi = 0; bi < 4; bi++) {
        const int row = wr + bi * 16 + l15;
        a[bi] = *(const bf16x8*)&As[row * 64 + (((lg + ks * 4) ^ (row & 7)) << 3)];
      }
#pragma unroll
      for (int bj = 0; bj < 4; bj++) {
        const int row = wc + bj * 16 + l15;
        b[bj] = *(const bf16x8*)&Bs[row * 64 + (((lg + ks * 4) ^ (row & 7)) << 3)];
      }
#pragma unroll
      for (int bi = 0; bi < 4; bi++)
#pragma unroll
        for (int bj = 0; bj < 4; bj++) acc[bi][bj] = MFMA16(a[bi], b[bj], acc[bi][bj]);
    }
  }
  // epilogue: +bias; Q scaled into exp2 domain; V stored transposed [d][s]
#pragma unroll
  for (int bj = 0; bj < 4; bj++) {
    const int n = bn * 128 + wc + bj * 16 + l15;
    const float bias = qkvb[n];
    const int which = (n >= 1536) ? 2 : (n >= 768 ? 1 : 0);
    const int c = n - which * 768;
    const int h = c >> 6, d = c & 63;
    if (which < 2) {
      unsigned short* dst = which == 0 ? Qb : Kb;
      const float scale = (which == 0) ? QSCALE : 1.0f;
#pragma unroll
      for (int bi = 0; bi < 4; bi++) {
#pragma unroll
        for (int r = 0; r < 4; r++) {
          const int rowm = mbase + wr + bi * 16 + lg * 4 + r;
          const int bb = rowm >> 10, s = rowm & 1023;
          dst[(((size_t)(mod * NB + bb) * NH + h) * SEQ + s) * HD + d] =
              f2bf((acc[bi][bj][r] + bias) * scale);
        }
      }
    } else {
#pragma unroll
      for (int bi = 0; bi < 4; bi++) {
        const int rowm0 = mbase + wr + bi * 16 + lg * 4;
        const int bb = rowm0 >> 10, s0 = rowm0 & 1023;
        u16x4 pk;
#pragma unroll
        for (int r = 0; r < 4; r++) pk[r] = f2bf(acc[bi][bj][r] + bias);
        *(u16x4*)&Vb[(((size_t)(mod * NB + bb) * NH + h) * HD + d) * SEQ + s0] = pk;
      }
    }
  }
}

// ---------- fused dual-modality flash attention ----------
__global__ __launch_bounds__(256, 3) void k_attn(
    const unsigned short* __restrict__ Qb, const unsigned short* __restrict__ Kb,
    const unsigned short* __restrict__ Vb, unsigned short* __restrict__ chi,
    unsigned short* __restrict__ clo) {
  __shared__ unsigned short Ks[2][4096];   // [64 s][64 d], source-swizzled
  __shared__ unsigned short Vts[2][4096];  // [64 d][64 s], source-swizzled
  __shared__ unsigned short Ps[4][2][16][72];
  const int tid = threadIdx.x, lane = tid & 63, wid = tid >> 6;
  const int l15 = lane & 15, lg = lane >> 4;
  const int qt = blockIdx.x, bh = blockIdx.y;

  bf16x8 qf[2][2];
#pragma unroll
  for (int m2 = 0; m2 < 2; m2++) {
    size_t base = ((size_t)(m2 * 48 + bh) * SEQ + qt * 64 + wid * 16 + l15) * HD;
#pragma unroll
    for (int ks = 0; ks < 2; ks++) qf[m2][ks] = *(const bf16x8*)&Qb[base + lg * 8 + ks * 32];
  }

  float m_[2][4], l_[2][4];
#pragma unroll
  for (int m2 = 0; m2 < 2; m2++)
#pragma unroll
    for (int r = 0; r < 4; r++) { m_[m2][r] = -1e30f; l_[m2][r] = 0.f; }
  f32x4 zero = {0.f, 0.f, 0.f, 0.f};
  f32x4 O[2][2][4];
#pragma unroll
  for (int a = 0; a < 2; a++)
#pragma unroll
    for (int v = 0; v < 2; v++)
#pragma unroll
      for (int c = 0; c < 4; c++) O[a][v][c] = zero;

  for (int kt = 0; kt < 16; ++kt) {
    __syncthreads();
    // stage K and V^T tiles (both mods) via global_load_lds, source-swizzled
#pragma unroll
    for (int m2 = 0; m2 < 2; m2++) {
      const size_t khead = ((size_t)(m2 * 48 + bh) * SEQ + kt * 64) * HD;  // shorts
      const size_t vhead = (size_t)(m2 * 48 + bh) * HD * SEQ;              // shorts
#pragma unroll
      for (int j = 0; j < 2; j++) {
        const int cb = wid * 2048 + j * 1024;  // byte chunk base (uniform)
        const int Lb = cb + lane * 16;
        const int row = Lb >> 7, c16 = (Lb >> 4) & 7;
        const int sc16 = c16 ^ (row & 7);
        GLOAD_LDS16(Kb + khead + (size_t)row * HD + sc16 * 8, (char*)&Ks[m2][0] + cb);
        GLOAD_LDS16(Vb + vhead + (size_t)row * SEQ + kt * 64 + sc16 * 8,
                    (char*)&Vts[m2][0] + cb);
      }
    }
    __syncthreads();
    // QK^T + online softmax (exp2 domain) per modality
#pragma unroll
    for (int m2 = 0; m2 < 2; m2++) {
      f32x4 s[4];
#pragma unroll
      for (int kb = 0; kb < 4; kb++) s[kb] = zero;
#pragma unroll
      for (int ks = 0; ks < 2; ks++) {
#pragma unroll
        for (int kb = 0; kb < 4; kb++) {
          const int krow = kb * 16 + l15;
          bf16x8 kf = *(const bf16x8*)&Ks[m2][krow * 64 + (((lg + ks * 4) ^ (krow & 7)) << 3)];
          s[kb] = MFMA16(qf[m2][ks], kf, s[kb]);
        }
      }
      float tm[4];
#pragma unroll
      for (int r = 0; r < 4; r++) {
        tm[r] = fmaxf(fmaxf(s[0][r], s[1][r]), fmaxf(s[2][r], s[3][r]));
#pragma unroll
        for (int msk = 1; msk < 16; msk <<= 1) tm[r] = fmaxf(tm[r], __shfl_xor(tm[r], msk));
      }
      bool ok = true;
#pragma unroll
      for (int r = 0; r < 4; r++) ok &= (tm[r] <= m_[m2][r] + 8.0f);
      if (!__all(ok)) {  // rescale path (rare after first tile)
        float sc[4];
#pragma unroll
        for (int r = 0; r < 4; r++) {
          float mn = fmaxf(m_[m2][r], tm[r]);
          sc[r] = exp2f(m_[m2][r] - mn);
          m_[m2][r] = mn;
          l_[m2][r] *= sc[r];
        }
#pragma unroll
        for (int v = 0; v < 2; v++)
#pragma unroll
          for (int db = 0; db < 4; db++)
#pragma unroll
            for (int r = 0; r < 4; r++) O[m2][v][db][r] *= sc[r];
      }
      float rs[4];
#pragma unroll
      for (int r = 0; r < 4; r++) {
        rs[r] = 0.f;
        float p[4];
#pragma unroll
        for (int kb = 0; kb < 4; kb++) {
          p[kb] = exp2f(s[kb][r] - m_[m2][r]);
          rs[r] += p[kb];
          Ps[wid][m2][lg * 4 + r][kb * 16 + l15] = f2bf(p[kb]);
        }
      }
#pragma unroll
      for (int r = 0; r < 4; r++) {
#pragma unroll
        for (int msk = 1; msk < 16; msk <<= 1) rs[r] += __shfl_xor(rs[r], msk);
        l_[m2][r] += rs[r];
      }
    }
    // PV: 4 combinations, V-fragments hoisted per k-step
    __builtin_amdgcn_s_setprio(1);
#pragma unroll
    for (int ks = 0; ks < 2; ++ks) {
      bf16x8 af0 = *(const bf16x8*)&Ps[wid][0][l15][lg * 8 + ks * 32];
      bf16x8 af1 = *(const bf16x8*)&Ps[wid][1][l15][lg * 8 + ks * 32];
#pragma unroll
      for (int vm = 0; vm < 2; vm++) {
#pragma unroll
        for (int db = 0; db < 4; db++) {
          const int vrow = db * 16 + l15;
          bf16x8 vf = *(const bf16x8*)&Vts[vm][vrow * 64 + (((lg + ks * 4) ^ (vrow & 7)) << 3)];
          O[0][vm][db] = MFMA16(af0, vf, O[0][vm][db]);
          O[1][vm][db] = MFMA16(af1, vf, O[1][vm][db]);
        }
      }
    }
    __builtin_amdgcn_s_setprio(0);
  }
  // finalize: blend, split to bf16 hi/lo ctx
  const int bb = bh / 12, h = bh - bb * 12;
  float inv[2][4];
#pragma unroll
  for (int m2 = 0; m2 < 2; m2++)
#pragma unroll
    for (int r = 0; r < 4; r++) inv[m2][r] = 1.f / l_[m2][r];
  const int qrow = qt * 64 + wid * 16 + lg * 4;
#pragma unroll
  for (int db = 0; db < 4; db++) {
#pragma unroll
    for (int r = 0; r < 4; r++) {
      const float ci = 0.7f * O[0][0][db][r] * inv[0][r] + 0.3f * O[1][0][db][r] * inv[1][r];
      const float cd = 0.7f * O[1][1][db][r] * inv[1][r] + 0.3f * O[0][1][db][r] * inv[0][r];
      const size_t col = h * 64 + db * 16 + l15;
      const size_t ri = (size_t)(bb * SEQ + qrow + r) * HID + col;
      const size_t rd = ri + (size_t)4096 * HID;
      unsigned short hh = f2bf(ci);
      chi[ri] = hh;
      clo[ri] = f2bf(ci - bf2f(hh));
      hh = f2bf(cd);
      chi[rd] = hh;
      clo[rd] = f2bf(cd - bf2f(hh));
    }
  }
}

// ---------- out projection: split-bf16 3-product GEMM, BK=64, async staging ----------
__global__ __launch_bounds__(256, 2) void k_outproj(
    const unsigned short* __restrict__ chi, const unsigned short* __restrict__ clo,
    const unsigned short* __restrict__ whi, const unsigned short* __restrict__ wlo,
    const float* __restrict__ outb, float* __restrict__ out) {
  __shared__ unsigned short Ahi[128 * 64], Alo[128 * 64], Bhi[128 * 64], Blo[128 * 64];
  const int tid = threadIdx.x, lane = tid & 63, wid = tid >> 6;
  const int wr = (wid >> 1) * 64, wc = (wid & 1) * 64;
  const int l15 = lane & 15, lg = lane >> 4;
  const int bn = blockIdx.x, bm = blockIdx.y;
  f32x4 zero = {0.f, 0.f, 0.f, 0.f};
  f32x4 acc[4][4];
#pragma unroll
  for (int i = 0; i < 4; i++)
#pragma unroll
    for (int j = 0; j < 4; j++) acc[i][j] = zero;

  for (int kt = 0; kt < 12; ++kt) {
    __syncthreads();
#pragma unroll
    for (int j = 0; j < 4; j++) {
      const int Lb = wid * 4096 + j * 1024 + lane * 16;
      const int row = Lb >> 7, c16 = (Lb >> 4) & 7;
      const int sc16 = c16 ^ (row & 7);
      const size_t aoff = (size_t)(bm * 128 + row) * HID + kt * 64 + sc16 * 8;
      const size_t boff = (size_t)(bn * 128 + row) * HID + kt * 64 + sc16 * 8;
      const int lo_ = wid * 4096 + j * 1024;
      GLOAD_LDS16(chi + aoff, (char*)Ahi + lo_);
      GLOAD_LDS16(clo + aoff, (char*)Alo + lo_);
      GLOAD_LDS16(whi + boff, (char*)Bhi + lo_);
      GLOAD_LDS16(wlo + boff, (char*)Blo + lo_);
    }
    __syncthreads();
#pragma unroll
    for (int ks = 0; ks < 2; ++ks) {
      bf16x8 ah[4], al[4], bh2[4], bl2[4];
#pragma unroll
      for (int bi = 0; bi < 4; bi++) {
        const int row = wr + bi * 16 + l15;
        const int off = row * 64 + (((lg + ks * 4) ^ (row & 7)) << 3);
        ah[bi] = *(const bf16x8*)&Ahi[off];
        al[bi] = *(const bf16x8*)&Alo[off];
      }
#pragma unroll
      for (int bj = 0; bj < 4; bj++) {
        const int row = wc + bj * 16 + l15;
        const int off = row * 64 + (((lg + ks * 4) ^ (row & 7)) << 3);
        bh2[bj] = *(const bf16x8*)&Bhi[off];
        bl2[bj] = *(const bf16x8*)&Blo[off];
      }
#pragma unroll
      for (int bi = 0; bi < 4; bi++)
#pragma unroll
        for (int bj = 0; bj < 4; bj++) {
          acc[bi][bj] = MFMA16(ah[bi], bh2[bj], acc[bi][bj]);
          acc[bi][bj] = MFMA16(ah[bi], bl2[bj], acc[bi][bj]);
          acc[bi][bj] = MFMA16(al[bi], bh2[bj], acc[bi][bj]);
        }
    }
  }
#pragma unroll
  for (int bj = 0; bj < 4; bj++) {
    const int n = bn * 128 + wc + bj * 16 + l15;
    const float bias = outb[n];
#pragma unroll
    for (int bi = 0; bi < 4; bi++) {
#pragma unroll
      for (int r = 0; r < 4; r++) {
        const int m = bm * 128 + wr + bi * 16 + lg * 4 + r;
        const int mod = m >> 12, mm = m & 4095;
        out[(size_t)mod * 3145728 + (size_t)mm * HID + n] = acc[bi][bj][r] + bias;
      }
    }
  }
}

// ---------- launcher ----------
extern "C" void kernel_launch(void* const* d_in, const int* in_sizes, int n_in,
                              void* d_out, int out_size, void* d_ws, size_t ws_size,
                              hipStream_t stream) {
  const float* img = (const float*)d_in[0];
  const float* dpt = (const float*)d_in[1];
  const float* qkv_w = (const float*)d_in[2];
  const float* qkv_b = (const float*)d_in[3];
  const float* out_w = (const float*)d_in[4];
  const float* out_b = (const float*)d_in[5];
  float* out = (float*)d_out;

  char* ws = (char*)d_ws;
  size_t off = 0;
  // region0: Xb (12.58MB) reused later as ctx hi/lo (25.17MB total)
  unsigned short* Xb = (unsigned short*)(ws + off);
  unsigned short* chi = (unsigned short*)(ws + off);
  unsigned short* clo = (unsigned short*)(ws + off + (size_t)8192 * HID * 2);
  off += (size_t)2 * 8192 * HID * 2;  // 25,165,824
  unsigned short* w1t = (unsigned short*)(ws + off); off += (size_t)N1 * HID * 2;
  unsigned short* w2hi = (unsigned short*)(ws + off); off += (size_t)HID * HID * 2;
  unsigned short* w2lo = (unsigned short*)(ws + off); off += (size_t)HID * HID * 2;
  unsigned short* Qb = (unsigned short*)(ws + off); off += (size_t)2 * 48 * SEQ * HD * 2;
  unsigned short* Kb = (unsigned short*)(ws + off); off += (size_t)2 * 48 * SEQ * HD * 2;
  unsigned short* Vb = (unsigned short*)(ws + off); off += (size_t)2 * 48 * SEQ * HD * 2;
  if (ws_size < off) return;  // 68,812,800 B required

  k_conv_x<<<3072, 256, 0, stream>>>(img, dpt, Xb);
  k_trans_w1<<<dim3(36, 12), 256, 0, stream>>>(qkv_w, w1t);
  k_trans_w2<<<dim3(12, 12), 256, 0, stream>>>(out_w, w2hi, w2lo);
  k_qkv<<<dim3(18, 64), 256, 0, stream>>>(Xb, w1t, qkv_b, Qb, Kb, Vb);
  k_attn<<<dim3(16, 48), 256, 0, stream>>>(Qb, Kb, Vb, chi, clo);
  k_outproj<<<dim3(6, 64), 256, 0, stream>>>(chi, clo, w2hi, w2lo, out_b, out);
}